// Round 13
// baseline (373.397 us; speedup 1.0000x reference)
//
#include <hip/hip_runtime.h>
#include <float.h>
#include <math.h>

#define TT 6
#define NN 3200
#define EE 32000
#define BB 8
#define GF 128
#define TOKF 512
#define NHH 8
#define PCH 16   // pooling chunks per graph

typedef __attribute__((ext_vector_type(4))) float f32x4;
typedef __attribute__((ext_vector_type(8))) short short8;

static __device__ __forceinline__ float leaky(float v){ return fmaxf(v, 0.2f*v); }
static __device__ __forceinline__ ushort f2bf(float f) {
  uint u = __float_as_uint(f);
  uint r = (u + 0x7fffu + ((u >> 16) & 1u)) >> 16;
  return (ushort)r;
}
static __device__ __forceinline__ float bflo(uint u){ return __uint_as_float(u << 16); }
static __device__ __forceinline__ float bfhi(uint u){ return __uint_as_float(u & 0xffff0000u); }

// ---------------- tiled f32 GEMM (proj only): C = A@W + bias ----------------
__global__ __launch_bounds__(256) void gemm_tiled(
    const float* __restrict__ A, int lda,
    const float* __restrict__ W, int ldw,
    const float* __restrict__ bias,
    float* __restrict__ C, int ldc,
    int M, int N, int K)
{
  __shared__ float As[64][36];
  __shared__ float Bs[32][64];
  int tid = threadIdx.x;
  int tx = tid & 15, ty = tid >> 4;
  int m0 = blockIdx.y * 64, n0 = blockIdx.x * 64;
  float acc[4][4] = {};
  for (int k0 = 0; k0 < K; k0 += 32) {
    #pragma unroll
    for (int i = 0; i < 2; ++i) {
      int q = tid + i * 256;
      int r = q >> 3, k = (q & 7) * 4;
      *(float4*)&As[r][k] = *(const float4*)&A[(size_t)(m0 + r) * lda + k0 + k];
    }
    #pragma unroll
    for (int i = 0; i < 2; ++i) {
      int q = tid + i * 256;
      int kk = q >> 4, c = (q & 15) * 4;
      *(float4*)&Bs[kk][c] = *(const float4*)&W[(size_t)(k0 + kk) * ldw + n0 + c];
    }
    __syncthreads();
    #pragma unroll
    for (int kk = 0; kk < 32; ++kk) {
      float4 b4 = *(const float4*)&Bs[kk][tx * 4];
      float a0 = As[ty*4+0][kk];
      float a1 = As[ty*4+1][kk];
      float a2 = As[ty*4+2][kk];
      float a3 = As[ty*4+3][kk];
      acc[0][0] += a0*b4.x; acc[0][1] += a0*b4.y; acc[0][2] += a0*b4.z; acc[0][3] += a0*b4.w;
      acc[1][0] += a1*b4.x; acc[1][1] += a1*b4.y; acc[1][2] += a1*b4.z; acc[1][3] += a1*b4.w;
      acc[2][0] += a2*b4.x; acc[2][1] += a2*b4.y; acc[2][2] += a2*b4.z; acc[2][3] += a2*b4.w;
      acc[3][0] += a3*b4.x; acc[3][1] += a3*b4.y; acc[3][2] += a3*b4.z; acc[3][3] += a3*b4.w;
    }
    __syncthreads();
  }
  float4 bia = *(const float4*)&bias[n0 + tx * 4];
  #pragma unroll
  for (int i = 0; i < 4; ++i) {
    float4 v = { acc[i][0] + bia.x, acc[i][1] + bia.y, acc[i][2] + bia.z, acc[i][3] + bia.w };
    *(float4*)&C[(size_t)(m0 + ty*4 + i) * ldc + n0 + tx * 4] = v;
  }
}

// ---------------- weight prep for ALL 3 GAT layers ----------------
__global__ void k_wprep3(const float* __restrict__ gat_wl, const float* __restrict__ gat_wr,
                         ushort* __restrict__ Wt3)
{
  int gid = blockIdx.x * 256 + threadIdx.x;
  if (gid >= 3 * 1024 * 128) return;
  int l = gid >> 17;
  int rem = gid & (1024 * 128 - 1);
  int n = rem >> 7, k = rem & 127;
  const float* wl = gat_wl + (size_t)l * 128 * 512;
  const float* wr = gat_wr + (size_t)l * 128 * 512;
  float v = (n < 512) ? wl[(size_t)k * 512 + n] : wr[(size_t)k * 512 + (n - 512)];
  Wt3[gid] = f2bf(v);
}

// ---------------- MFMA GAT xl/xr GEMM (R10 measured form) ----------------
__global__ __launch_bounds__(256) void gat_lr_gemm_mfma(
    const float* __restrict__ A,      // [M][128] f32
    const ushort* __restrict__ Wt,    // [1024][128] bf16
    const float* __restrict__ bl, const float* __restrict__ br,
    ushort* __restrict__ C)           // [M][1024] bf16
{
  __shared__ ushort Asm[64 * 128];
  __shared__ ushort Wsm[64 * 128];
  int tid = threadIdx.x;
  int m0 = blockIdx.y * 64, n0 = blockIdx.x * 64;

  #pragma unroll
  for (int i = 0; i < 4; ++i) {
    int g = tid + i * 256;
    int row = g >> 4, gk = g & 15;
    const float* src = A + (size_t)(m0 + row) * 128 + gk * 8;
    float4 f0 = *(const float4*)src;
    float4 f1 = *(const float4*)(src + 4);
    short8 hv;
    hv[0] = (short)f2bf(f0.x); hv[1] = (short)f2bf(f0.y);
    hv[2] = (short)f2bf(f0.z); hv[3] = (short)f2bf(f0.w);
    hv[4] = (short)f2bf(f1.x); hv[5] = (short)f2bf(f1.y);
    hv[6] = (short)f2bf(f1.z); hv[7] = (short)f2bf(f1.w);
    *(short8*)&Asm[row * 128 + (gk ^ (row & 7)) * 8] = hv;
  }
  #pragma unroll
  for (int i = 0; i < 4; ++i) {
    int g = tid + i * 256;
    int col = g >> 4, gk = g & 15;
    short8 raw = *(const short8*)&Wt[(size_t)(n0 + col) * 128 + gk * 8];
    *(short8*)&Wsm[col * 128 + (gk ^ (col & 7)) * 8] = raw;
  }
  __syncthreads();

  int l = tid & 63, wv = tid >> 6;
  int wr_ = wv >> 1, wc_ = wv & 1;
  int lr = l & 15, lk = l >> 4;
  f32x4 acc[2][2] = {};
  #pragma unroll
  for (int ks = 0; ks < 4; ++ks) {
    int g = ks * 4 + lk;
    int ra0 = wr_ * 32 + lr,      ra1 = wr_ * 32 + 16 + lr;
    int rb0 = wc_ * 32 + lr,      rb1 = wc_ * 32 + 16 + lr;
    short8 a0 = *(short8*)&Asm[ra0 * 128 + (g ^ (ra0 & 7)) * 8];
    short8 a1 = *(short8*)&Asm[ra1 * 128 + (g ^ (ra1 & 7)) * 8];
    short8 b0 = *(short8*)&Wsm[rb0 * 128 + (g ^ (rb0 & 7)) * 8];
    short8 b1 = *(short8*)&Wsm[rb1 * 128 + (g ^ (rb1 & 7)) * 8];
    acc[0][0] = __builtin_amdgcn_mfma_f32_16x16x32_bf16(a0, b0, acc[0][0], 0, 0, 0);
    acc[0][1] = __builtin_amdgcn_mfma_f32_16x16x32_bf16(a0, b1, acc[0][1], 0, 0, 0);
    acc[1][0] = __builtin_amdgcn_mfma_f32_16x16x32_bf16(a1, b0, acc[1][0], 0, 0, 0);
    acc[1][1] = __builtin_amdgcn_mfma_f32_16x16x32_bf16(a1, b1, acc[1][1], 0, 0, 0);
  }

  int col_l = l & 15, row_l = (l >> 4) * 4;
  #pragma unroll
  for (int fn = 0; fn < 2; ++fn) {
    int n_g = n0 + wc_ * 32 + fn * 16 + col_l;
    float bia = (n_g < 512) ? bl[n_g] : br[n_g - 512];
    #pragma unroll
    for (int fm = 0; fm < 2; ++fm) {
      #pragma unroll
      for (int r = 0; r < 4; ++r) {
        int m = m0 + wr_ * 32 + fm * 16 + row_l + r;
        C[(size_t)m * 1024 + n_g] = f2bf(acc[fm][fn][r] + bia);
      }
    }
  }
}

// ---------------- split-K skinny GEMM (M=48) ----------------
__global__ __launch_bounds__(256) void gemm_part(
    const float* __restrict__ A, int lda,
    const float* __restrict__ W, int ldw,
    float* __restrict__ P, int N)
{
  __shared__ float As[48][132];
  __shared__ float Ws[128][32];
  int tid = threadIdx.x;
  int n0 = blockIdx.x * 32, k0 = blockIdx.y * 128;
  #pragma unroll
  for (int i = 0; i < 6; ++i) {
    int q = tid + i * 256;
    int m = q >> 5, k = (q & 31) * 4;
    *(float4*)&As[m][k] = *(const float4*)&A[(size_t)m * lda + k0 + k];
  }
  #pragma unroll
  for (int i = 0; i < 4; ++i) {
    int q = tid + i * 256;
    int k = q >> 3, c = (q & 7) * 4;
    *(float4*)&Ws[k][c] = *(const float4*)&W[(size_t)(k0 + k) * ldw + n0 + c];
  }
  __syncthreads();
  int tx = tid & 31, ty = tid >> 5;
  float acc[6] = {};
  #pragma unroll 4
  for (int k = 0; k < 128; ++k) {
    float w = Ws[k][tx];
    #pragma unroll
    for (int i = 0; i < 6; ++i) acc[i] += As[ty + 8*i][k] * w;
  }
  size_t base = (size_t)blockIdx.y * 48 * N;
  #pragma unroll
  for (int i = 0; i < 6; ++i)
    P[base + (size_t)(ty + 8*i) * N + n0 + tx] = acc[i];
}

// split-K GEMM whose A is relu(bias + sum of nparts partials) of a previous split-K
// A logical layout: [48][2048]; partials Pin[p][48][2048]
__global__ __launch_bounds__(256) void gemm_part_pr(
    const float* __restrict__ Pin, int npartsA, const float* __restrict__ biasA,
    const float* __restrict__ W, int ldw,
    float* __restrict__ P, int N)
{
  __shared__ float As[48][132];
  __shared__ float Ws[128][32];
  int tid = threadIdx.x;
  int n0 = blockIdx.x * 32, k0 = blockIdx.y * 128;
  const int MNA = 48 * 2048;
  #pragma unroll
  for (int i = 0; i < 6; ++i) {
    int q = tid + i * 256;
    int m = q >> 5, k = (q & 31) * 4;
    size_t base = (size_t)m * 2048 + k0 + k;
    float4 s = *(const float4*)&biasA[k0 + k];
    for (int p = 0; p < 4; ++p) {
      float4 v = *(const float4*)&Pin[(size_t)p * MNA + base];
      s.x += v.x; s.y += v.y; s.z += v.z; s.w += v.w;
    }
    s.x = fmaxf(s.x, 0.f); s.y = fmaxf(s.y, 0.f);
    s.z = fmaxf(s.z, 0.f); s.w = fmaxf(s.w, 0.f);
    *(float4*)&As[m][k] = s;
  }
  #pragma unroll
  for (int i = 0; i < 4; ++i) {
    int q = tid + i * 256;
    int k = q >> 3, c = (q & 7) * 4;
    *(float4*)&Ws[k][c] = *(const float4*)&W[(size_t)(k0 + k) * ldw + n0 + c];
  }
  __syncthreads();
  int tx = tid & 31, ty = tid >> 5;
  float acc[6] = {};
  #pragma unroll 4
  for (int k = 0; k < 128; ++k) {
    float w = Ws[k][tx];
    #pragma unroll
    for (int i = 0; i < 6; ++i) acc[i] += As[ty + 8*i][k] * w;
  }
  size_t base = (size_t)blockIdx.y * 48 * N;
  #pragma unroll
  for (int i = 0; i < 6; ++i)
    P[base + (size_t)(ty + 8*i) * N + n0 + tx] = acc[i];
}

// n2t reduce: writes happ[b][t][:] directly
__global__ void k_n2t_reduce(const float* __restrict__ P, const float* __restrict__ bias,
                             float* __restrict__ happ)
{
  int i = blockIdx.x * 256 + threadIdx.x;
  if (i >= 48 * 512) return;
  int j = i & 511, r = i >> 9;
  int t = r >> 3, b = r & 7;
  float s = bias[j];
  #pragma unroll
  for (int p = 0; p < 2; ++p) s += P[(size_t)p * 48 * 512 + i];
  happ[((size_t)(b * TT) + t) * 512 + j] = s;
}

// ---------------- CSR build ----------------
__global__ void k_hist(const int* __restrict__ edge_index, int* __restrict__ cnt)
{
  int gid = blockIdx.x * 256 + threadIdx.x;
  if (gid >= TT * EE) return;
  int t = gid / EE, e = gid - t * EE;
  int dst = edge_index[t * 2 * EE + EE + e];
  atomicAdd(&cnt[t * NN + dst], 1);
}

__global__ __launch_bounds__(256) void k_scan(const int* __restrict__ cnt, int* __restrict__ row)
{
  __shared__ int part[256];
  int t = blockIdx.x, tid = threadIdx.x;
  const int chunk = (NN + 255) / 256;
  int s0 = tid * chunk;
  int loc = 0;
  for (int i = 0; i < chunk; ++i) { int idx = s0 + i; if (idx < NN) loc += cnt[t*NN + idx]; }
  part[tid] = loc; __syncthreads();
  for (int off = 1; off < 256; off <<= 1) {
    int v = (tid >= off) ? part[tid - off] : 0;
    __syncthreads();
    part[tid] += v;
    __syncthreads();
  }
  int run = part[tid] - loc;
  for (int i = 0; i < chunk; ++i) {
    int idx = s0 + i;
    if (idx < NN) { row[t*(NN+1) + idx] = run; run += cnt[t*NN + idx]; }
  }
  if (tid == 255) row[t*(NN+1) + NN] = part[255];
}

// scatter: CSR-permute srcs AND edge_attr
__global__ void k_scatter(const int* __restrict__ edge_index, const float* __restrict__ ea,
                          const int* __restrict__ row, int* __restrict__ cur,
                          int* __restrict__ srcs, float2* __restrict__ ea_csr)
{
  int gid = blockIdx.x * 256 + threadIdx.x;
  if (gid >= TT * EE) return;
  int t = gid / EE, e = gid - t * EE;
  int src = edge_index[t * 2 * EE + e];
  int dst = edge_index[t * 2 * EE + EE + e];
  float2 ev = *(const float2*)&ea[((size_t)t * EE + e) * 2];
  int pos = row[t*(NN+1) + dst] + atomicAdd(&cur[t*NN + dst], 1);
  int s = t * EE + pos;
  srcs[s] = src;
  ea_csr[s] = ev;
}

__global__ void k_gstart(const int* __restrict__ batch, int* __restrict__ gs)
{
  int n = blockIdx.x * 256 + threadIdx.x;
  if (n >= NN) return;
  int bc = batch[n];
  if (n == 0) { for (int j = 0; j <= bc; ++j) gs[j] = 0; }
  else { int bp = batch[n-1]; for (int j = bp + 1; j <= bc; ++j) gs[j] = n; }
  if (n == NN - 1) { for (int j = bc + 1; j <= BB; ++j) gs[j] = NN; }
}

// ======== FUSED GAT, fixed-ref softmax, TWO waves per node ========
// block 256 = 4 waves = 2 nodes x 2 half-segments. Fixed-reference softmax makes
// the two halves' (ssum, acc) partials directly addable — combined via LDS + 1 barrier.
__global__ __launch_bounds__(256) void k_gat_fused1w(
    const ushort* __restrict__ xlr, const int* __restrict__ row,
    const int* __restrict__ srcs, const float2* __restrict__ ea_csr,
    const float* __restrict__ we, const float* __restrict__ att,
    const float* __restrict__ bias,
    const float* __restrict__ lng, const float* __restrict__ lnb,
    const float* __restrict__ h_in, float* __restrict__ h_out)
{
  __shared__ float sacc[4][64][9];      // [wave][lane][acc0..7, ssum]
  int wv = threadIdx.x >> 6, l = threadIdx.x & 63;
  int t = blockIdx.y;
  int n = blockIdx.x * 2 + (wv >> 1);   // 2 nodes per block
  int half = wv & 1;
  int hd = l >> 4, q = l & 15;
  int ub = hd * 64 + q * 4;             // uint index into 512-ch row
  float2 w0[4], w1[4], at4[4];
  #pragma unroll
  for (int j = 0; j < 4; ++j) {
    int j0 = (ub + j) * 2;
    w0[j]  = make_float2(we[j0],        we[j0 + 1]);
    w1[j]  = make_float2(we[512 + j0],  we[512 + j0 + 1]);
    at4[j] = make_float2(att[j0],       att[j0 + 1]);
  }
  int seg0 = row[t * (NN + 1) + n];
  int seg1 = row[t * (NN + 1) + n + 1];
  int len  = seg1 - seg0;
  int h0len = (len + 1) >> 1;
  int start = half ? seg0 + h0len : seg0;
  int end   = half ? seg1 : seg0 + h0len;

  // xr[dst=n] into registers
  const uint* xd = (const uint*)(xlr + ((size_t)t * NN + n) * 1024 + 512);
  uint4 ud = *(const uint4*)&xd[ub];
  float xrv[8];
  xrv[0] = bflo(ud.x); xrv[1] = bfhi(ud.x);
  xrv[2] = bflo(ud.y); xrv[3] = bfhi(ud.y);
  xrv[4] = bflo(ud.z); xrv[5] = bfhi(ud.z);
  xrv[6] = bflo(ud.w); xrv[7] = bfhi(ud.w);

  size_t sb = (size_t)t * EE;
  const ushort* xbase = xlr + (size_t)t * NN * 1024;

  float ssum = 0.f;
  float acc[8] = {};

  auto edge_proc = [&](uint4 us, float2 eav) {
    float xv[8];
    xv[0] = bflo(us.x); xv[1] = bfhi(us.x);
    xv[2] = bflo(us.y); xv[3] = bfhi(us.y);
    xv[4] = bflo(us.z); xv[5] = bfhi(us.z);
    xv[6] = bflo(us.w); xv[7] = bfhi(us.w);
    float lg = 0.f;
    #pragma unroll
    for (int j = 0; j < 4; ++j) {
      float lo = xv[2*j] + xrv[2*j];
      lo = fmaf(eav.x, w0[j].x, lo);
      lo = fmaf(eav.y, w1[j].x, lo);
      lg = fmaf(leaky(lo), at4[j].x, lg);
      float hi = xv[2*j+1] + xrv[2*j+1];
      hi = fmaf(eav.x, w0[j].y, hi);
      hi = fmaf(eav.y, w1[j].y, hi);
      lg = fmaf(leaky(hi), at4[j].y, lg);
    }
    lg += __shfl_xor(lg, 1, 64);
    lg += __shfl_xor(lg, 2, 64);
    lg += __shfl_xor(lg, 4, 64);
    lg += __shfl_xor(lg, 8, 64);
    float w = __expf(fminf(lg, 60.f));
    ssum += w;
    #pragma unroll
    for (int j = 0; j < 8; ++j) acc[j] = fmaf(w, xv[j], acc[j]);
  };

  int p = start;
  for (; p + 4 <= end; p += 4) {
    int sA = srcs[sb + p],     sB = srcs[sb + p + 1];
    int sC = srcs[sb + p + 2], sD = srcs[sb + p + 3];
    float2 eA = ea_csr[sb + p],     eB = ea_csr[sb + p + 1];
    float2 eC = ea_csr[sb + p + 2], eD = ea_csr[sb + p + 3];
    uint4 uA = *(const uint4*)&((const uint*)(xbase + (size_t)sA * 1024))[ub];
    uint4 uB = *(const uint4*)&((const uint*)(xbase + (size_t)sB * 1024))[ub];
    uint4 uC = *(const uint4*)&((const uint*)(xbase + (size_t)sC * 1024))[ub];
    uint4 uD = *(const uint4*)&((const uint*)(xbase + (size_t)sD * 1024))[ub];
    edge_proc(uA, eA);
    edge_proc(uB, eB);
    edge_proc(uC, eC);
    edge_proc(uD, eD);
  }
  for (; p < end; ++p) {
    int sA = srcs[sb + p];
    float2 eA = ea_csr[sb + p];
    uint4 uA = *(const uint4*)&((const uint*)(xbase + (size_t)sA * 1024))[ub];
    edge_proc(uA, eA);
  }

  // publish partials; even waves combine
  #pragma unroll
  for (int j = 0; j < 8; ++j) sacc[wv][l][j] = acc[j];
  sacc[wv][l][8] = ssum;
  __syncthreads();
  if (half) return;
  #pragma unroll
  for (int j = 0; j < 8; ++j) acc[j] += sacc[wv + 1][l][j];
  ssum += sacc[wv + 1][l][8];

  // normalize
  float inv = 1.f / (ssum + 1e-16f);
  #pragma unroll
  for (int j = 0; j < 8; ++j) acc[j] *= inv;

  // head mean: sum across the 4 16-lane groups
  #pragma unroll
  for (int j = 0; j < 8; ++j) {
    float v = acc[j];
    v += __shfl_xor(v, 16, 64);
    v += __shfl_xor(v, 32, 64);
    acc[j] = v * 0.25f;
  }

  // bias + relu + residual
  const float* hin = h_in + ((size_t)t * NN + n) * 128 + q * 8;
  float4 hi0 = *(const float4*)hin;
  float4 hi1 = *(const float4*)(hin + 4);
  float4 bi0 = *(const float4*)&bias[q * 8];
  float4 bi1 = *(const float4*)&bias[q * 8 + 4];
  float val[8];
  val[0] = fmaxf(acc[0] + bi0.x, 0.f) + hi0.x;
  val[1] = fmaxf(acc[1] + bi0.y, 0.f) + hi0.y;
  val[2] = fmaxf(acc[2] + bi0.z, 0.f) + hi0.z;
  val[3] = fmaxf(acc[3] + bi0.w, 0.f) + hi0.w;
  val[4] = fmaxf(acc[4] + bi1.x, 0.f) + hi1.x;
  val[5] = fmaxf(acc[5] + bi1.y, 0.f) + hi1.y;
  val[6] = fmaxf(acc[6] + bi1.z, 0.f) + hi1.z;
  val[7] = fmaxf(acc[7] + bi1.w, 0.f) + hi1.w;

  // LayerNorm over 128 channels: reduce (sum, sumsq) across the 16-lane group
  float s1 = 0.f, s2 = 0.f;
  #pragma unroll
  for (int j = 0; j < 8; ++j) { s1 += val[j]; s2 += val[j] * val[j]; }
  #pragma unroll
  for (int o = 1; o < 16; o <<= 1) {
    s1 += __shfl_xor(s1, o, 64);
    s2 += __shfl_xor(s2, o, 64);
  }
  float mu = s1 * (1.f / 128.f);
  float var = fmaxf(s2 * (1.f / 128.f) - mu * mu, 0.f);
  float rstd = rsqrtf(var + 1e-5f);
  if (hd == 0) {
    float4 g0 = *(const float4*)&lng[q * 8];
    float4 g1 = *(const float4*)&lng[q * 8 + 4];
    float4 b0 = *(const float4*)&lnb[q * 8];
    float4 b1 = *(const float4*)&lnb[q * 8 + 4];
    float4 o0, o1;
    o0.x = (val[0] - mu) * rstd * g0.x + b0.x;
    o0.y = (val[1] - mu) * rstd * g0.y + b0.y;
    o0.z = (val[2] - mu) * rstd * g0.z + b0.z;
    o0.w = (val[3] - mu) * rstd * g0.w + b0.w;
    o1.x = (val[4] - mu) * rstd * g1.x + b1.x;
    o1.y = (val[5] - mu) * rstd * g1.y + b1.y;
    o1.z = (val[6] - mu) * rstd * g1.z + b1.z;
    o1.w = (val[7] - mu) * rstd * g1.w + b1.w;
    float* hout = h_out + ((size_t)t * NN + n) * 128 + q * 8;
    *(float4*)hout = o0;
    *(float4*)(hout + 4) = o1;
  }
}

// ---------------- graph pooling, two-stage ----------------
__global__ __launch_bounds__(128) void k_pool1(
    const float* __restrict__ h, const int* __restrict__ gs, float* __restrict__ part)
{
  int b = blockIdx.x, t = blockIdx.y, ch = blockIdx.z, c = threadIdx.x;
  int s0 = gs[b], s1 = gs[b + 1];
  int len = s1 - s0;
  int per = (len + PCH - 1) / PCH;
  int a0 = s0 + ch * per;
  int a1 = min(a0 + per, s1);
  float sum = 0.f, mx = -FLT_MAX;
  for (int n = a0; n < a1; ++n) {
    float v = h[((size_t)t * NN + n) * 128 + c];
    sum += v; mx = fmaxf(mx, v);
  }
  size_t o = (((size_t)(t * BB + b) * PCH + ch) * 2) * 128 + c;
  part[o] = sum; part[o + 128] = mx;
}

__global__ __launch_bounds__(128) void k_pool2(
    const float* __restrict__ part, const int* __restrict__ gs, float* __restrict__ pooled)
{
  int b = blockIdx.x, t = blockIdx.y, c = threadIdx.x;
  float sum = 0.f, mx = -FLT_MAX;
  for (int ch = 0; ch < PCH; ++ch) {
    size_t o = (((size_t)(t * BB + b) * PCH + ch) * 2) * 128 + c;
    sum += part[o]; mx = fmaxf(mx, part[o + 128]);
  }
  int cnt = gs[b + 1] - gs[b]; if (cnt < 1) cnt = 1;
  pooled[((size_t)t * BB + b) * 256 + c] = sum / (float)cnt;
  pooled[((size_t)t * BB + b) * 256 + 128 + c] = mx;
}

// ---------------- motion diff output (reads happ[B][T][512]) ----------------
__global__ void k_mot(const float* __restrict__ happ, float* __restrict__ out2)
{
  int gid = blockIdx.x * 256 + threadIdx.x;
  if (gid >= BB * (TT - 1) * 256) return;
  int b = gid / ((TT - 1) * 256);
  int r = gid - b * ((TT - 1) * 256);
  int ti = r / 256, cc = r - ti * 256;
  out2[gid] = happ[((size_t)(b * TT) + ti + 1) * 512 + cc]
            - happ[((size_t)(b * TT) + ti) * 512 + cc];
}

// ---------------- tiny MHA (reads split-K qkv partials directly) ----------------
__global__ __launch_bounds__(64) void k_attn(const float* __restrict__ P,
                                             const float* __restrict__ bias,
                                             float* __restrict__ aout)
{
  __shared__ float qs[TT][64], ks[TT][64], vs[TT][64], sc[TT][TT];
  int h = blockIdx.x, b = blockIdx.y, d = threadIdx.x;
  const int MN = 48 * 1536;
  float bq = bias[h * 64 + d], bk = bias[512 + h * 64 + d], bv = bias[1024 + h * 64 + d];
  for (int i = 0; i < TT; ++i) {
    size_t base = ((size_t)(b * TT + i)) * 1536 + h * 64 + d;
    float q = bq, k = bk, v = bv;
    #pragma unroll
    for (int p = 0; p < 4; ++p) {
      q += P[(size_t)p * MN + base];
      k += P[(size_t)p * MN + base + 512];
      v += P[(size_t)p * MN + base + 1024];
    }
    qs[i][d] = q; ks[i][d] = k; vs[i][d] = v;
  }
  __syncthreads();
  if (d < TT * TT) {
    int i = d / TT, j = d - i * TT;
    float s = 0.f;
    for (int k = 0; k < 64; ++k) s += qs[i][k] * ks[j][k];
    sc[i][j] = s * 0.125f;
  }
  __syncthreads();
  if (d < TT) {
    float mx = -FLT_MAX;
    for (int j = 0; j < TT; ++j) mx = fmaxf(mx, sc[d][j]);
    float sum = 0.f;
    for (int j = 0; j < TT; ++j) { float e = expf(sc[d][j] - mx); sc[d][j] = e; sum += e; }
    float inv = 1.f / sum;
    for (int j = 0; j < TT; ++j) sc[d][j] *= inv;
  }
  __syncthreads();
  for (int i = 0; i < TT; ++i) {
    float o = 0.f;
    for (int j = 0; j < TT; ++j) o += sc[i][j] * vs[j][d];
    aout[((size_t)(b * TT + i)) * 512 + h * 64 + d] = o;
  }
}

// ---------------- residual + LayerNorm from split-K partials (width 512) ----------------
__global__ __launch_bounds__(256) void k_res_ln_p(
    const float* __restrict__ P, int nparts, const float* __restrict__ bias,
    const float* __restrict__ r,
    const float* __restrict__ g, const float* __restrict__ be,
    float* __restrict__ out)
{
  __shared__ float2 wred[4];
  int rowi = blockIdx.x, tid = threadIdx.x;
  size_t base = (size_t)rowi * 512;
  const int MN = 48 * 512;
  float v0 = bias[tid], v1 = bias[256 + tid];
  for (int p = 0; p < nparts; ++p) {
    v0 += P[(size_t)p * MN + base + tid];
    v1 += P[(size_t)p * MN + base + 256 + tid];
  }
  v0 += r[base + tid];
  v1 += r[base + 256 + tid];
  float s1 = v0 + v1, s2 = v0 * v0 + v1 * v1;
  #pragma unroll
  for (int o = 32; o > 0; o >>= 1) {
    s1 += __shfl_xor(s1, o, 64);
    s2 += __shfl_xor(s2, o, 64);
  }
  int wv = tid >> 6, l = tid & 63;
  if (l == 0) wred[wv] = make_float2(s1, s2);
  __syncthreads();
  float t1 = wred[0].x + wred[1].x + wred[2].x + wred[3].x;
  float t2 = wred[0].y + wred[1].y + wred[2].y + wred[3].y;
  float mu = t1 * (1.f / 512.f);
  float var = fmaxf(t2 * (1.f / 512.f) - mu * mu, 0.f);
  float rstd = rsqrtf(var + 1e-5f);
  out[base + tid]       = (v0 - mu) * rstd * g[tid]       + be[tid];
  out[base + 256 + tid] = (v1 - mu) * rstd * g[256 + tid] + be[256 + tid];
}

extern "C" void kernel_launch(void* const* d_in, const int* in_sizes, int n_in,
                              void* d_out, int out_size, void* d_ws, size_t ws_size,
                              hipStream_t stream)
{
  const float* x        = (const float*)d_in[0];
  const int*   eidx     = (const int*)  d_in[1];
  const float* eattr    = (const float*)d_in[2];
  const int*   batch    = (const int*)  d_in[3];
  const float* proj_w   = (const float*)d_in[4];
  const float* proj_b   = (const float*)d_in[5];
  const float* gat_wl   = (const float*)d_in[6];
  const float* gat_bl   = (const float*)d_in[7];
  const float* gat_wr   = (const float*)d_in[8];
  const float* gat_br   = (const float*)d_in[9];
  const float* gat_we   = (const float*)d_in[10];
  const float* gat_att  = (const float*)d_in[11];
  const float* gat_bias = (const float*)d_in[12];
  const float* ln_g     = (const float*)d_in[13];
  const float* ln_b     = (const float*)d_in[14];
  const float* n2t_w    = (const float*)d_in[15];
  const float* n2t_b    = (const float*)d_in[16];
  const float* tf_wqkv  = (const float*)d_in[17];
  const float* tf_bqkv  = (const float*)d_in[18];
  const float* tf_wo    = (const float*)d_in[19];
  const float* tf_bo    = (const float*)d_in[20];
  const float* tf_w1    = (const float*)d_in[21];
  const float* tf_b1    = (const float*)d_in[22];
  const float* tf_w2    = (const float*)d_in[23];
  const float* tf_b2    = (const float*)d_in[24];
  const float* tf_ln1g  = (const float*)d_in[25];
  const float* tf_ln1b  = (const float*)d_in[26];
  const float* tf_ln2g  = (const float*)d_in[27];
  const float* tf_ln2b  = (const float*)d_in[28];

  char* ws = (char*)d_ws;
  size_t off = 0;
  auto alloc = [&](size_t bytes) -> char* {
    char* p = ws + off;
    off += (bytes + 255) & ~(size_t)255;
    return p;
  };
  int*    cnt    = (int*)   alloc((size_t)TT * NN * 4);
  int*    row    = (int*)   alloc((size_t)TT * (NN + 1) * 4);
  int*    srcs   = (int*)   alloc((size_t)TT * EE * 4);
  float2* ea_csr = (float2*)alloc((size_t)TT * EE * 8);
  int*    gs     = (int*)   alloc((BB + 1) * 4);
  float*  h0     = (float*) alloc((size_t)TT * NN * 128 * 4);
  float*  h1     = (float*) alloc((size_t)TT * NN * 128 * 4);
  ushort* xlr    = (ushort*)alloc((size_t)TT * NN * 1024 * 2);   // bf16
  ushort* Wt3    = (ushort*)alloc((size_t)3 * 1024 * 128 * 2);   // bf16 weights, all layers
  float*  part   = (float*) alloc((size_t)TT * BB * PCH * 2 * 128 * 4);
  float*  pooled = (float*) alloc((size_t)TT * BB * 256 * 4);
  float*  happ   = (float*) alloc((size_t)BB * TT * 512 * 4);
  float*  happ2  = (float*) alloc((size_t)BB * TT * 512 * 4);
  float*  aoutb  = (float*) alloc((size_t)BB * TT * 512 * 4);
  float*  P2     = (float*) alloc((size_t)16 * 48 * 512 * 4);    // w2 split-K partials
  if (off > ws_size) return;

  // split-K partial buffer aliases xlr (dead after GAT phase)
  float* P = (float*)xlr;

  // ---- CSR build per timestep ----
  hipMemsetAsync(cnt, 0, (size_t)TT * NN * 4, stream);
  k_hist<<<(TT * EE + 255) / 256, 256, 0, stream>>>(eidx, cnt);
  k_scan<<<TT, 256, 0, stream>>>(cnt, row);
  hipMemsetAsync(cnt, 0, (size_t)TT * NN * 4, stream);
  k_scatter<<<(TT * EE + 255) / 256, 256, 0, stream>>>(eidx, eattr, row, cnt, srcs, ea_csr);
  k_gstart<<<(NN + 255) / 256, 256, 0, stream>>>(batch, gs);

  // ---- weight prep (all 3 GAT layers) + input projection ----
  k_wprep3<<<(3 * 1024 * 128 + 255) / 256, 256, 0, stream>>>(gat_wl, gat_wr, Wt3);
  gemm_tiled<<<dim3(2, (TT * NN) / 64), 256, 0, stream>>>(
      x, 128, proj_w, 128, proj_b, h0, 128, TT * NN, 128, 128);

  // ---- GAT layers (fused single-pass softmax, 2 waves/node) ----
  float* hcur = h0; float* hnext = h1;
  for (int l = 0; l < 3; ++l) {
    const float* bl  = gat_bl  + (size_t)l * 512;
    const float* br  = gat_br  + (size_t)l * 512;
    const float* we  = gat_we  + (size_t)l * 2 * 512;
    const float* att = gat_att + (size_t)l * 512;
    gat_lr_gemm_mfma<<<dim3(16, 300), 256, 0, stream>>>(hcur, Wt3 + (size_t)l * 1024 * 128, bl, br, xlr);
    k_gat_fused1w<<<dim3(NN / 2, TT), 256, 0, stream>>>(xlr, row, srcs, ea_csr, we, att,
        gat_bias + l * 128, ln_g + l * 128, ln_b + l * 128, hcur, hnext);
    float* tmp = hcur; hcur = hnext; hnext = tmp;
  }

  // ---- pooling + token projection (writes happ transposed) + motion diff ----
  k_pool1<<<dim3(BB, TT, PCH), 128, 0, stream>>>(hcur, gs, part);
  k_pool2<<<dim3(BB, TT), 128, 0, stream>>>(part, gs, pooled);
  gemm_part<<<dim3(512 / 32, 2), 256, 0, stream>>>(pooled, 256, n2t_w, 512, P, 512);
  k_n2t_reduce<<<(48 * 512 + 255) / 256, 256, 0, stream>>>(P, n2t_b, happ);
  k_mot<<<(BB * (TT - 1) * 256 + 255) / 256, 256, 0, stream>>>(happ, (float*)d_out + BB * TT * TOKF);

  // ---- transformer encoder ----
  float* hx = happ;
  for (int l = 0; l < 2; ++l) {
    gemm_part<<<dim3(1536 / 32, 4), 256, 0, stream>>>(hx, 512,
        tf_wqkv + (size_t)l * 512 * 1536, 1536, P, 1536);
    k_attn<<<dim3(NHH, BB), 64, 0, stream>>>(P, tf_bqkv + l * 1536, aoutb);
    gemm_part<<<dim3(512 / 32, 4), 256, 0, stream>>>(aoutb, 512,
        tf_wo + (size_t)l * 512 * 512, 512, P, 512);
    k_res_ln_p<<<BB * TT, 256, 0, stream>>>(P, 4, tf_bo + l * 512, hx,
        tf_ln1g + l * 512, tf_ln1b + l * 512, happ2);
    // FF: w1 partials -> P ; w2 reads relu(bias+P) directly, writes partials -> P2
    gemm_part<<<dim3(2048 / 32, 4), 256, 0, stream>>>(happ2, 512,
        tf_w1 + (size_t)l * 512 * 2048, 2048, P, 2048);
    gemm_part_pr<<<dim3(512 / 32, 16), 256, 0, stream>>>(P, 4, tf_b1 + l * 2048,
        tf_w2 + (size_t)l * 2048 * 512, 512, P2, 512);
    float* dst = (l == 1) ? (float*)d_out : happ;
    k_res_ln_p<<<BB * TT, 256, 0, stream>>>(P2, 16, tf_b2 + l * 512, happ2,
        tf_ln2g + l * 512, tf_ln2b + l * 512, dst);
    hx = happ;
  }
}

// Round 14
// 352.628 us; speedup vs baseline: 1.0589x; 1.0589x over previous
//
#include <hip/hip_runtime.h>
#include <float.h>
#include <math.h>

#define TT 6
#define NN 3200
#define EE 32000
#define BB 8
#define GF 128
#define TOKF 512
#define NHH 8
#define PCH 16   // pooling chunks per graph

typedef __attribute__((ext_vector_type(4))) float f32x4;
typedef __attribute__((ext_vector_type(8))) short short8;

static __device__ __forceinline__ float leaky(float v){ return fmaxf(v, 0.2f*v); }
static __device__ __forceinline__ ushort f2bf(float f) {
  uint u = __float_as_uint(f);
  uint r = (u + 0x7fffu + ((u >> 16) & 1u)) >> 16;
  return (ushort)r;
}
static __device__ __forceinline__ float bflo(uint u){ return __uint_as_float(u << 16); }
static __device__ __forceinline__ float bfhi(uint u){ return __uint_as_float(u & 0xffff0000u); }

// ---------------- tiled f32 GEMM (proj only): C = A@W + bias ----------------
__global__ __launch_bounds__(256) void gemm_tiled(
    const float* __restrict__ A, int lda,
    const float* __restrict__ W, int ldw,
    const float* __restrict__ bias,
    float* __restrict__ C, int ldc,
    int M, int N, int K)
{
  __shared__ float As[64][36];
  __shared__ float Bs[32][64];
  int tid = threadIdx.x;
  int tx = tid & 15, ty = tid >> 4;
  int m0 = blockIdx.y * 64, n0 = blockIdx.x * 64;
  float acc[4][4] = {};
  for (int k0 = 0; k0 < K; k0 += 32) {
    #pragma unroll
    for (int i = 0; i < 2; ++i) {
      int q = tid + i * 256;
      int r = q >> 3, k = (q & 7) * 4;
      *(float4*)&As[r][k] = *(const float4*)&A[(size_t)(m0 + r) * lda + k0 + k];
    }
    #pragma unroll
    for (int i = 0; i < 2; ++i) {
      int q = tid + i * 256;
      int kk = q >> 4, c = (q & 15) * 4;
      *(float4*)&Bs[kk][c] = *(const float4*)&W[(size_t)(k0 + kk) * ldw + n0 + c];
    }
    __syncthreads();
    #pragma unroll
    for (int kk = 0; kk < 32; ++kk) {
      float4 b4 = *(const float4*)&Bs[kk][tx * 4];
      float a0 = As[ty*4+0][kk];
      float a1 = As[ty*4+1][kk];
      float a2 = As[ty*4+2][kk];
      float a3 = As[ty*4+3][kk];
      acc[0][0] += a0*b4.x; acc[0][1] += a0*b4.y; acc[0][2] += a0*b4.z; acc[0][3] += a0*b4.w;
      acc[1][0] += a1*b4.x; acc[1][1] += a1*b4.y; acc[1][2] += a1*b4.z; acc[1][3] += a1*b4.w;
      acc[2][0] += a2*b4.x; acc[2][1] += a2*b4.y; acc[2][2] += a2*b4.z; acc[2][3] += a2*b4.w;
      acc[3][0] += a3*b4.x; acc[3][1] += a3*b4.y; acc[3][2] += a3*b4.z; acc[3][3] += a3*b4.w;
    }
    __syncthreads();
  }
  float4 bia = *(const float4*)&bias[n0 + tx * 4];
  #pragma unroll
  for (int i = 0; i < 4; ++i) {
    float4 v = { acc[i][0] + bia.x, acc[i][1] + bia.y, acc[i][2] + bia.z, acc[i][3] + bia.w };
    *(float4*)&C[(size_t)(m0 + ty*4 + i) * ldc + n0 + tx * 4] = v;
  }
}

// ---------------- weight prep for ALL 3 GAT layers ----------------
__global__ void k_wprep3(const float* __restrict__ gat_wl, const float* __restrict__ gat_wr,
                         ushort* __restrict__ Wt3)
{
  int gid = blockIdx.x * 256 + threadIdx.x;
  if (gid >= 3 * 1024 * 128) return;
  int l = gid >> 17;
  int rem = gid & (1024 * 128 - 1);
  int n = rem >> 7, k = rem & 127;
  const float* wl = gat_wl + (size_t)l * 128 * 512;
  const float* wr = gat_wr + (size_t)l * 128 * 512;
  float v = (n < 512) ? wl[(size_t)k * 512 + n] : wr[(size_t)k * 512 + (n - 512)];
  Wt3[gid] = f2bf(v);
}

// ---------------- MFMA GAT xl/xr GEMM (R10 measured form) ----------------
__global__ __launch_bounds__(256) void gat_lr_gemm_mfma(
    const float* __restrict__ A,      // [M][128] f32
    const ushort* __restrict__ Wt,    // [1024][128] bf16
    const float* __restrict__ bl, const float* __restrict__ br,
    ushort* __restrict__ C)           // [M][1024] bf16
{
  __shared__ ushort Asm[64 * 128];
  __shared__ ushort Wsm[64 * 128];
  int tid = threadIdx.x;
  int m0 = blockIdx.y * 64, n0 = blockIdx.x * 64;

  #pragma unroll
  for (int i = 0; i < 4; ++i) {
    int g = tid + i * 256;
    int row = g >> 4, gk = g & 15;
    const float* src = A + (size_t)(m0 + row) * 128 + gk * 8;
    float4 f0 = *(const float4*)src;
    float4 f1 = *(const float4*)(src + 4);
    short8 hv;
    hv[0] = (short)f2bf(f0.x); hv[1] = (short)f2bf(f0.y);
    hv[2] = (short)f2bf(f0.z); hv[3] = (short)f2bf(f0.w);
    hv[4] = (short)f2bf(f1.x); hv[5] = (short)f2bf(f1.y);
    hv[6] = (short)f2bf(f1.z); hv[7] = (short)f2bf(f1.w);
    *(short8*)&Asm[row * 128 + (gk ^ (row & 7)) * 8] = hv;
  }
  #pragma unroll
  for (int i = 0; i < 4; ++i) {
    int g = tid + i * 256;
    int col = g >> 4, gk = g & 15;
    short8 raw = *(const short8*)&Wt[(size_t)(n0 + col) * 128 + gk * 8];
    *(short8*)&Wsm[col * 128 + (gk ^ (col & 7)) * 8] = raw;
  }
  __syncthreads();

  int l = tid & 63, wv = tid >> 6;
  int wr_ = wv >> 1, wc_ = wv & 1;
  int lr = l & 15, lk = l >> 4;
  f32x4 acc[2][2] = {};
  #pragma unroll
  for (int ks = 0; ks < 4; ++ks) {
    int g = ks * 4 + lk;
    int ra0 = wr_ * 32 + lr,      ra1 = wr_ * 32 + 16 + lr;
    int rb0 = wc_ * 32 + lr,      rb1 = wc_ * 32 + 16 + lr;
    short8 a0 = *(short8*)&Asm[ra0 * 128 + (g ^ (ra0 & 7)) * 8];
    short8 a1 = *(short8*)&Asm[ra1 * 128 + (g ^ (ra1 & 7)) * 8];
    short8 b0 = *(short8*)&Wsm[rb0 * 128 + (g ^ (rb0 & 7)) * 8];
    short8 b1 = *(short8*)&Wsm[rb1 * 128 + (g ^ (rb1 & 7)) * 8];
    acc[0][0] = __builtin_amdgcn_mfma_f32_16x16x32_bf16(a0, b0, acc[0][0], 0, 0, 0);
    acc[0][1] = __builtin_amdgcn_mfma_f32_16x16x32_bf16(a0, b1, acc[0][1], 0, 0, 0);
    acc[1][0] = __builtin_amdgcn_mfma_f32_16x16x32_bf16(a1, b0, acc[1][0], 0, 0, 0);
    acc[1][1] = __builtin_amdgcn_mfma_f32_16x16x32_bf16(a1, b1, acc[1][1], 0, 0, 0);
  }

  int col_l = l & 15, row_l = (l >> 4) * 4;
  #pragma unroll
  for (int fn = 0; fn < 2; ++fn) {
    int n_g = n0 + wc_ * 32 + fn * 16 + col_l;
    float bia = (n_g < 512) ? bl[n_g] : br[n_g - 512];
    #pragma unroll
    for (int fm = 0; fm < 2; ++fm) {
      #pragma unroll
      for (int r = 0; r < 4; ++r) {
        int m = m0 + wr_ * 32 + fm * 16 + row_l + r;
        C[(size_t)m * 1024 + n_g] = f2bf(acc[fm][fn][r] + bia);
      }
    }
  }
}

// ---------------- split-K skinny GEMM (M=48) ----------------
__global__ __launch_bounds__(256) void gemm_part(
    const float* __restrict__ A, int lda,
    const float* __restrict__ W, int ldw,
    float* __restrict__ P, int N)
{
  __shared__ float As[48][132];
  __shared__ float Ws[128][32];
  int tid = threadIdx.x;
  int n0 = blockIdx.x * 32, k0 = blockIdx.y * 128;
  #pragma unroll
  for (int i = 0; i < 6; ++i) {
    int q = tid + i * 256;
    int m = q >> 5, k = (q & 31) * 4;
    *(float4*)&As[m][k] = *(const float4*)&A[(size_t)m * lda + k0 + k];
  }
  #pragma unroll
  for (int i = 0; i < 4; ++i) {
    int q = tid + i * 256;
    int k = q >> 3, c = (q & 7) * 4;
    *(float4*)&Ws[k][c] = *(const float4*)&W[(size_t)(k0 + k) * ldw + n0 + c];
  }
  __syncthreads();
  int tx = tid & 31, ty = tid >> 5;
  float acc[6] = {};
  #pragma unroll 4
  for (int k = 0; k < 128; ++k) {
    float w = Ws[k][tx];
    #pragma unroll
    for (int i = 0; i < 6; ++i) acc[i] += As[ty + 8*i][k] * w;
  }
  size_t base = (size_t)blockIdx.y * 48 * N;
  #pragma unroll
  for (int i = 0; i < 6; ++i)
    P[base + (size_t)(ty + 8*i) * N + n0 + tx] = acc[i];
}

// split-K GEMM whose A is relu(bias + sum of 4 partials) of a previous split-K
// A logical layout: [48][2048]; partials Pin[p][48][2048]
__global__ __launch_bounds__(256) void gemm_part_pr(
    const float* __restrict__ Pin, int npartsA, const float* __restrict__ biasA,
    const float* __restrict__ W, int ldw,
    float* __restrict__ P, int N)
{
  __shared__ float As[48][132];
  __shared__ float Ws[128][32];
  int tid = threadIdx.x;
  int n0 = blockIdx.x * 32, k0 = blockIdx.y * 128;
  const int MNA = 48 * 2048;
  #pragma unroll
  for (int i = 0; i < 6; ++i) {
    int q = tid + i * 256;
    int m = q >> 5, k = (q & 31) * 4;
    size_t base = (size_t)m * 2048 + k0 + k;
    float4 s = *(const float4*)&biasA[k0 + k];
    for (int p = 0; p < 4; ++p) {
      float4 v = *(const float4*)&Pin[(size_t)p * MNA + base];
      s.x += v.x; s.y += v.y; s.z += v.z; s.w += v.w;
    }
    s.x = fmaxf(s.x, 0.f); s.y = fmaxf(s.y, 0.f);
    s.z = fmaxf(s.z, 0.f); s.w = fmaxf(s.w, 0.f);
    *(float4*)&As[m][k] = s;
  }
  #pragma unroll
  for (int i = 0; i < 4; ++i) {
    int q = tid + i * 256;
    int k = q >> 3, c = (q & 7) * 4;
    *(float4*)&Ws[k][c] = *(const float4*)&W[(size_t)(k0 + k) * ldw + n0 + c];
  }
  __syncthreads();
  int tx = tid & 31, ty = tid >> 5;
  float acc[6] = {};
  #pragma unroll 4
  for (int k = 0; k < 128; ++k) {
    float w = Ws[k][tx];
    #pragma unroll
    for (int i = 0; i < 6; ++i) acc[i] += As[ty + 8*i][k] * w;
  }
  size_t base = (size_t)blockIdx.y * 48 * N;
  #pragma unroll
  for (int i = 0; i < 6; ++i)
    P[base + (size_t)(ty + 8*i) * N + n0 + tx] = acc[i];
}

// n2t reduce: writes happ[b][t][:] directly
__global__ void k_n2t_reduce(const float* __restrict__ P, const float* __restrict__ bias,
                             float* __restrict__ happ)
{
  int i = blockIdx.x * 256 + threadIdx.x;
  if (i >= 48 * 512) return;
  int j = i & 511, r = i >> 9;
  int t = r >> 3, b = r & 7;
  float s = bias[j];
  #pragma unroll
  for (int p = 0; p < 2; ++p) s += P[(size_t)p * 48 * 512 + i];
  happ[((size_t)(b * TT) + t) * 512 + j] = s;
}

// ---------------- CSR build ----------------
__global__ void k_hist(const int* __restrict__ edge_index, int* __restrict__ cnt)
{
  int gid = blockIdx.x * 256 + threadIdx.x;
  if (gid >= TT * EE) return;
  int t = gid / EE, e = gid - t * EE;
  int dst = edge_index[t * 2 * EE + EE + e];
  atomicAdd(&cnt[t * NN + dst], 1);
}

__global__ __launch_bounds__(256) void k_scan(const int* __restrict__ cnt, int* __restrict__ row)
{
  __shared__ int part[256];
  int t = blockIdx.x, tid = threadIdx.x;
  const int chunk = (NN + 255) / 256;
  int s0 = tid * chunk;
  int loc = 0;
  for (int i = 0; i < chunk; ++i) { int idx = s0 + i; if (idx < NN) loc += cnt[t*NN + idx]; }
  part[tid] = loc; __syncthreads();
  for (int off = 1; off < 256; off <<= 1) {
    int v = (tid >= off) ? part[tid - off] : 0;
    __syncthreads();
    part[tid] += v;
    __syncthreads();
  }
  int run = part[tid] - loc;
  for (int i = 0; i < chunk; ++i) {
    int idx = s0 + i;
    if (idx < NN) { row[t*(NN+1) + idx] = run; run += cnt[t*NN + idx]; }
  }
  if (tid == 255) row[t*(NN+1) + NN] = part[255];
}

// scatter: CSR-permute srcs AND edge_attr
__global__ void k_scatter(const int* __restrict__ edge_index, const float* __restrict__ ea,
                          const int* __restrict__ row, int* __restrict__ cur,
                          int* __restrict__ srcs, float2* __restrict__ ea_csr)
{
  int gid = blockIdx.x * 256 + threadIdx.x;
  if (gid >= TT * EE) return;
  int t = gid / EE, e = gid - t * EE;
  int src = edge_index[t * 2 * EE + e];
  int dst = edge_index[t * 2 * EE + EE + e];
  float2 ev = *(const float2*)&ea[((size_t)t * EE + e) * 2];
  int pos = row[t*(NN+1) + dst] + atomicAdd(&cur[t*NN + dst], 1);
  int s = t * EE + pos;
  srcs[s] = src;
  ea_csr[s] = ev;
}

__global__ void k_gstart(const int* __restrict__ batch, int* __restrict__ gs)
{
  int n = blockIdx.x * 256 + threadIdx.x;
  if (n >= NN) return;
  int bc = batch[n];
  if (n == 0) { for (int j = 0; j <= bc; ++j) gs[j] = 0; }
  else { int bp = batch[n-1]; for (int j = bp + 1; j <= bc; ++j) gs[j] = n; }
  if (n == NN - 1) { for (int j = bc + 1; j <= BB; ++j) gs[j] = NN; }
}

// ======== FUSED GAT, single pass, fixed-reference softmax (measured-best form) ========
__global__ __launch_bounds__(256) void k_gat_fused1w(
    const ushort* __restrict__ xlr, const int* __restrict__ row,
    const int* __restrict__ srcs, const float2* __restrict__ ea_csr,
    const float* __restrict__ we, const float* __restrict__ att,
    const float* __restrict__ bias,
    const float* __restrict__ lng, const float* __restrict__ lnb,
    const float* __restrict__ h_in, float* __restrict__ h_out)
{
  int wv = threadIdx.x >> 6, l = threadIdx.x & 63;
  int t = blockIdx.y;
  int n = blockIdx.x * 4 + wv;
  int hd = l >> 4, q = l & 15;
  int ub = hd * 64 + q * 4;             // uint index into 512-ch row
  float2 w0[4], w1[4], at4[4];
  #pragma unroll
  for (int j = 0; j < 4; ++j) {
    int j0 = (ub + j) * 2;
    w0[j]  = make_float2(we[j0],        we[j0 + 1]);
    w1[j]  = make_float2(we[512 + j0],  we[512 + j0 + 1]);
    at4[j] = make_float2(att[j0],       att[j0 + 1]);
  }
  int start = row[t * (NN + 1) + n];
  int end   = row[t * (NN + 1) + n + 1];

  // xr[dst=n] into registers
  const uint* xd = (const uint*)(xlr + ((size_t)t * NN + n) * 1024 + 512);
  uint4 ud = *(const uint4*)&xd[ub];
  float xrv[8];
  xrv[0] = bflo(ud.x); xrv[1] = bfhi(ud.x);
  xrv[2] = bflo(ud.y); xrv[3] = bfhi(ud.y);
  xrv[4] = bflo(ud.z); xrv[5] = bfhi(ud.z);
  xrv[6] = bflo(ud.w); xrv[7] = bfhi(ud.w);

  size_t sb = (size_t)t * EE;
  const ushort* xbase = xlr + (size_t)t * NN * 1024;

  float ssum = 0.f;
  float acc[8] = {};

  auto edge_proc = [&](uint4 us, float2 eav) {
    float xv[8];
    xv[0] = bflo(us.x); xv[1] = bfhi(us.x);
    xv[2] = bflo(us.y); xv[3] = bfhi(us.y);
    xv[4] = bflo(us.z); xv[5] = bfhi(us.z);
    xv[6] = bflo(us.w); xv[7] = bfhi(us.w);
    float lg = 0.f;
    #pragma unroll
    for (int j = 0; j < 4; ++j) {
      float lo = xv[2*j] + xrv[2*j];
      lo = fmaf(eav.x, w0[j].x, lo);
      lo = fmaf(eav.y, w1[j].x, lo);
      lg = fmaf(leaky(lo), at4[j].x, lg);
      float hi = xv[2*j+1] + xrv[2*j+1];
      hi = fmaf(eav.x, w0[j].y, hi);
      hi = fmaf(eav.y, w1[j].y, hi);
      lg = fmaf(leaky(hi), at4[j].y, lg);
    }
    lg += __shfl_xor(lg, 1, 64);
    lg += __shfl_xor(lg, 2, 64);
    lg += __shfl_xor(lg, 4, 64);
    lg += __shfl_xor(lg, 8, 64);
    float w = __expf(fminf(lg, 60.f));
    ssum += w;
    #pragma unroll
    for (int j = 0; j < 8; ++j) acc[j] = fmaf(w, xv[j], acc[j]);
  };

  int p = start;
  for (; p + 4 <= end; p += 4) {
    int sA = srcs[sb + p],     sB = srcs[sb + p + 1];
    int sC = srcs[sb + p + 2], sD = srcs[sb + p + 3];
    float2 eA = ea_csr[sb + p],     eB = ea_csr[sb + p + 1];
    float2 eC = ea_csr[sb + p + 2], eD = ea_csr[sb + p + 3];
    uint4 uA = *(const uint4*)&((const uint*)(xbase + (size_t)sA * 1024))[ub];
    uint4 uB = *(const uint4*)&((const uint*)(xbase + (size_t)sB * 1024))[ub];
    uint4 uC = *(const uint4*)&((const uint*)(xbase + (size_t)sC * 1024))[ub];
    uint4 uD = *(const uint4*)&((const uint*)(xbase + (size_t)sD * 1024))[ub];
    edge_proc(uA, eA);
    edge_proc(uB, eB);
    edge_proc(uC, eC);
    edge_proc(uD, eD);
  }
  for (; p < end; ++p) {
    int sA = srcs[sb + p];
    float2 eA = ea_csr[sb + p];
    uint4 uA = *(const uint4*)&((const uint*)(xbase + (size_t)sA * 1024))[ub];
    edge_proc(uA, eA);
  }

  // normalize
  float inv = 1.f / (ssum + 1e-16f);
  #pragma unroll
  for (int j = 0; j < 8; ++j) acc[j] *= inv;

  // head mean: sum across the 4 16-lane groups
  #pragma unroll
  for (int j = 0; j < 8; ++j) {
    float v = acc[j];
    v += __shfl_xor(v, 16, 64);
    v += __shfl_xor(v, 32, 64);
    acc[j] = v * 0.25f;
  }

  // bias + relu + residual
  const float* hin = h_in + ((size_t)t * NN + n) * 128 + q * 8;
  float4 hi0 = *(const float4*)hin;
  float4 hi1 = *(const float4*)(hin + 4);
  float4 bi0 = *(const float4*)&bias[q * 8];
  float4 bi1 = *(const float4*)&bias[q * 8 + 4];
  float val[8];
  val[0] = fmaxf(acc[0] + bi0.x, 0.f) + hi0.x;
  val[1] = fmaxf(acc[1] + bi0.y, 0.f) + hi0.y;
  val[2] = fmaxf(acc[2] + bi0.z, 0.f) + hi0.z;
  val[3] = fmaxf(acc[3] + bi0.w, 0.f) + hi0.w;
  val[4] = fmaxf(acc[4] + bi1.x, 0.f) + hi1.x;
  val[5] = fmaxf(acc[5] + bi1.y, 0.f) + hi1.y;
  val[6] = fmaxf(acc[6] + bi1.z, 0.f) + hi1.z;
  val[7] = fmaxf(acc[7] + bi1.w, 0.f) + hi1.w;

  // LayerNorm over 128 channels: reduce (sum, sumsq) across the 16-lane group
  float s1 = 0.f, s2 = 0.f;
  #pragma unroll
  for (int j = 0; j < 8; ++j) { s1 += val[j]; s2 += val[j] * val[j]; }
  #pragma unroll
  for (int o = 1; o < 16; o <<= 1) {
    s1 += __shfl_xor(s1, o, 64);
    s2 += __shfl_xor(s2, o, 64);
  }
  float mu = s1 * (1.f / 128.f);
  float var = fmaxf(s2 * (1.f / 128.f) - mu * mu, 0.f);
  float rstd = rsqrtf(var + 1e-5f);
  if (hd == 0) {
    float4 g0 = *(const float4*)&lng[q * 8];
    float4 g1 = *(const float4*)&lng[q * 8 + 4];
    float4 b0 = *(const float4*)&lnb[q * 8];
    float4 b1 = *(const float4*)&lnb[q * 8 + 4];
    float4 o0, o1;
    o0.x = (val[0] - mu) * rstd * g0.x + b0.x;
    o0.y = (val[1] - mu) * rstd * g0.y + b0.y;
    o0.z = (val[2] - mu) * rstd * g0.z + b0.z;
    o0.w = (val[3] - mu) * rstd * g0.w + b0.w;
    o1.x = (val[4] - mu) * rstd * g1.x + b1.x;
    o1.y = (val[5] - mu) * rstd * g1.y + b1.y;
    o1.z = (val[6] - mu) * rstd * g1.z + b1.z;
    o1.w = (val[7] - mu) * rstd * g1.w + b1.w;
    float* hout = h_out + ((size_t)t * NN + n) * 128 + q * 8;
    *(float4*)hout = o0;
    *(float4*)(hout + 4) = o1;
  }
}

// ---------------- graph pooling, two-stage ----------------
__global__ __launch_bounds__(128) void k_pool1(
    const float* __restrict__ h, const int* __restrict__ gs, float* __restrict__ part)
{
  int b = blockIdx.x, t = blockIdx.y, ch = blockIdx.z, c = threadIdx.x;
  int s0 = gs[b], s1 = gs[b + 1];
  int len = s1 - s0;
  int per = (len + PCH - 1) / PCH;
  int a0 = s0 + ch * per;
  int a1 = min(a0 + per, s1);
  float sum = 0.f, mx = -FLT_MAX;
  for (int n = a0; n < a1; ++n) {
    float v = h[((size_t)t * NN + n) * 128 + c];
    sum += v; mx = fmaxf(mx, v);
  }
  size_t o = (((size_t)(t * BB + b) * PCH + ch) * 2) * 128 + c;
  part[o] = sum; part[o + 128] = mx;
}

__global__ __launch_bounds__(128) void k_pool2(
    const float* __restrict__ part, const int* __restrict__ gs, float* __restrict__ pooled)
{
  int b = blockIdx.x, t = blockIdx.y, c = threadIdx.x;
  float sum = 0.f, mx = -FLT_MAX;
  for (int ch = 0; ch < PCH; ++ch) {
    size_t o = (((size_t)(t * BB + b) * PCH + ch) * 2) * 128 + c;
    sum += part[o]; mx = fmaxf(mx, part[o + 128]);
  }
  int cnt = gs[b + 1] - gs[b]; if (cnt < 1) cnt = 1;
  pooled[((size_t)t * BB + b) * 256 + c] = sum / (float)cnt;
  pooled[((size_t)t * BB + b) * 256 + 128 + c] = mx;
}

// ---------------- motion diff output (reads happ[B][T][512]) ----------------
__global__ void k_mot(const float* __restrict__ happ, float* __restrict__ out2)
{
  int gid = blockIdx.x * 256 + threadIdx.x;
  if (gid >= BB * (TT - 1) * 256) return;
  int b = gid / ((TT - 1) * 256);
  int r = gid - b * ((TT - 1) * 256);
  int ti = r / 256, cc = r - ti * 256;
  out2[gid] = happ[((size_t)(b * TT) + ti + 1) * 512 + cc]
            - happ[((size_t)(b * TT) + ti) * 512 + cc];
}

// ---------------- tiny MHA (reads split-K qkv partials directly) ----------------
__global__ __launch_bounds__(64) void k_attn(const float* __restrict__ P,
                                             const float* __restrict__ bias,
                                             float* __restrict__ aout)
{
  __shared__ float qs[TT][64], ks[TT][64], vs[TT][64], sc[TT][TT];
  int h = blockIdx.x, b = blockIdx.y, d = threadIdx.x;
  const int MN = 48 * 1536;
  float bq = bias[h * 64 + d], bk = bias[512 + h * 64 + d], bv = bias[1024 + h * 64 + d];
  for (int i = 0; i < TT; ++i) {
    size_t base = ((size_t)(b * TT + i)) * 1536 + h * 64 + d;
    float q = bq, k = bk, v = bv;
    #pragma unroll
    for (int p = 0; p < 4; ++p) {
      q += P[(size_t)p * MN + base];
      k += P[(size_t)p * MN + base + 512];
      v += P[(size_t)p * MN + base + 1024];
    }
    qs[i][d] = q; ks[i][d] = k; vs[i][d] = v;
  }
  __syncthreads();
  if (d < TT * TT) {
    int i = d / TT, j = d - i * TT;
    float s = 0.f;
    for (int k = 0; k < 64; ++k) s += qs[i][k] * ks[j][k];
    sc[i][j] = s * 0.125f;
  }
  __syncthreads();
  if (d < TT) {
    float mx = -FLT_MAX;
    for (int j = 0; j < TT; ++j) mx = fmaxf(mx, sc[d][j]);
    float sum = 0.f;
    for (int j = 0; j < TT; ++j) { float e = expf(sc[d][j] - mx); sc[d][j] = e; sum += e; }
    float inv = 1.f / sum;
    for (int j = 0; j < TT; ++j) sc[d][j] *= inv;
  }
  __syncthreads();
  for (int i = 0; i < TT; ++i) {
    float o = 0.f;
    for (int j = 0; j < TT; ++j) o += sc[i][j] * vs[j][d];
    aout[((size_t)(b * TT + i)) * 512 + h * 64 + d] = o;
  }
}

// ---------------- residual + LayerNorm from split-K partials (width 512) ----------------
__global__ __launch_bounds__(256) void k_res_ln_p(
    const float* __restrict__ P, int nparts, const float* __restrict__ bias,
    const float* __restrict__ r,
    const float* __restrict__ g, const float* __restrict__ be,
    float* __restrict__ out)
{
  __shared__ float2 wred[4];
  int rowi = blockIdx.x, tid = threadIdx.x;
  size_t base = (size_t)rowi * 512;
  const int MN = 48 * 512;
  float v0 = bias[tid], v1 = bias[256 + tid];
  for (int p = 0; p < nparts; ++p) {
    v0 += P[(size_t)p * MN + base + tid];
    v1 += P[(size_t)p * MN + base + 256 + tid];
  }
  v0 += r[base + tid];
  v1 += r[base + 256 + tid];
  float s1 = v0 + v1, s2 = v0 * v0 + v1 * v1;
  #pragma unroll
  for (int o = 32; o > 0; o >>= 1) {
    s1 += __shfl_xor(s1, o, 64);
    s2 += __shfl_xor(s2, o, 64);
  }
  int wv = tid >> 6, l = tid & 63;
  if (l == 0) wred[wv] = make_float2(s1, s2);
  __syncthreads();
  float t1 = wred[0].x + wred[1].x + wred[2].x + wred[3].x;
  float t2 = wred[0].y + wred[1].y + wred[2].y + wred[3].y;
  float mu = t1 * (1.f / 512.f);
  float var = fmaxf(t2 * (1.f / 512.f) - mu * mu, 0.f);
  float rstd = rsqrtf(var + 1e-5f);
  out[base + tid]       = (v0 - mu) * rstd * g[tid]       + be[tid];
  out[base + 256 + tid] = (v1 - mu) * rstd * g[256 + tid] + be[256 + tid];
}

extern "C" void kernel_launch(void* const* d_in, const int* in_sizes, int n_in,
                              void* d_out, int out_size, void* d_ws, size_t ws_size,
                              hipStream_t stream)
{
  const float* x        = (const float*)d_in[0];
  const int*   eidx     = (const int*)  d_in[1];
  const float* eattr    = (const float*)d_in[2];
  const int*   batch    = (const int*)  d_in[3];
  const float* proj_w   = (const float*)d_in[4];
  const float* proj_b   = (const float*)d_in[5];
  const float* gat_wl   = (const float*)d_in[6];
  const float* gat_bl   = (const float*)d_in[7];
  const float* gat_wr   = (const float*)d_in[8];
  const float* gat_br   = (const float*)d_in[9];
  const float* gat_we   = (const float*)d_in[10];
  const float* gat_att  = (const float*)d_in[11];
  const float* gat_bias = (const float*)d_in[12];
  const float* ln_g     = (const float*)d_in[13];
  const float* ln_b     = (const float*)d_in[14];
  const float* n2t_w    = (const float*)d_in[15];
  const float* n2t_b    = (const float*)d_in[16];
  const float* tf_wqkv  = (const float*)d_in[17];
  const float* tf_bqkv  = (const float*)d_in[18];
  const float* tf_wo    = (const float*)d_in[19];
  const float* tf_bo    = (const float*)d_in[20];
  const float* tf_w1    = (const float*)d_in[21];
  const float* tf_b1    = (const float*)d_in[22];
  const float* tf_w2    = (const float*)d_in[23];
  const float* tf_b2    = (const float*)d_in[24];
  const float* tf_ln1g  = (const float*)d_in[25];
  const float* tf_ln1b  = (const float*)d_in[26];
  const float* tf_ln2g  = (const float*)d_in[27];
  const float* tf_ln2b  = (const float*)d_in[28];

  char* ws = (char*)d_ws;
  size_t off = 0;
  auto alloc = [&](size_t bytes) -> char* {
    char* p = ws + off;
    off += (bytes + 255) & ~(size_t)255;
    return p;
  };
  int*    cnt    = (int*)   alloc((size_t)TT * NN * 4);
  int*    row    = (int*)   alloc((size_t)TT * (NN + 1) * 4);
  int*    srcs   = (int*)   alloc((size_t)TT * EE * 4);
  float2* ea_csr = (float2*)alloc((size_t)TT * EE * 8);
  int*    gs     = (int*)   alloc((BB + 1) * 4);
  float*  h0     = (float*) alloc((size_t)TT * NN * 128 * 4);
  float*  h1     = (float*) alloc((size_t)TT * NN * 128 * 4);
  ushort* xlr    = (ushort*)alloc((size_t)TT * NN * 1024 * 2);   // bf16
  ushort* Wt3    = (ushort*)alloc((size_t)3 * 1024 * 128 * 2);   // bf16 weights, all layers
  float*  part   = (float*) alloc((size_t)TT * BB * PCH * 2 * 128 * 4);
  float*  pooled = (float*) alloc((size_t)TT * BB * 256 * 4);
  float*  happ   = (float*) alloc((size_t)BB * TT * 512 * 4);
  float*  happ2  = (float*) alloc((size_t)BB * TT * 512 * 4);
  float*  aoutb  = (float*) alloc((size_t)BB * TT * 512 * 4);
  float*  P2     = (float*) alloc((size_t)16 * 48 * 512 * 4);    // w2 split-K partials
  if (off > ws_size) return;

  // split-K partial buffer aliases xlr (dead after GAT phase)
  float* P = (float*)xlr;

  // ---- CSR build per timestep ----
  hipMemsetAsync(cnt, 0, (size_t)TT * NN * 4, stream);
  k_hist<<<(TT * EE + 255) / 256, 256, 0, stream>>>(eidx, cnt);
  k_scan<<<TT, 256, 0, stream>>>(cnt, row);
  hipMemsetAsync(cnt, 0, (size_t)TT * NN * 4, stream);
  k_scatter<<<(TT * EE + 255) / 256, 256, 0, stream>>>(eidx, eattr, row, cnt, srcs, ea_csr);
  k_gstart<<<(NN + 255) / 256, 256, 0, stream>>>(batch, gs);

  // ---- weight prep (all 3 GAT layers) + input projection ----
  k_wprep3<<<(3 * 1024 * 128 + 255) / 256, 256, 0, stream>>>(gat_wl, gat_wr, Wt3);
  gemm_tiled<<<dim3(2, (TT * NN) / 64), 256, 0, stream>>>(
      x, 128, proj_w, 128, proj_b, h0, 128, TT * NN, 128, 128);

  // ---- GAT layers (fused single-pass softmax) ----
  float* hcur = h0; float* hnext = h1;
  for (int l = 0; l < 3; ++l) {
    const float* bl  = gat_bl  + (size_t)l * 512;
    const float* br  = gat_br  + (size_t)l * 512;
    const float* we  = gat_we  + (size_t)l * 2 * 512;
    const float* att = gat_att + (size_t)l * 512;
    gat_lr_gemm_mfma<<<dim3(16, 300), 256, 0, stream>>>(hcur, Wt3 + (size_t)l * 1024 * 128, bl, br, xlr);
    k_gat_fused1w<<<dim3(NN / 4, TT), 256, 0, stream>>>(xlr, row, srcs, ea_csr, we, att,
        gat_bias + l * 128, ln_g + l * 128, ln_b + l * 128, hcur, hnext);
    float* tmp = hcur; hcur = hnext; hnext = tmp;
  }

  // ---- pooling + token projection (writes happ transposed) + motion diff ----
  k_pool1<<<dim3(BB, TT, PCH), 128, 0, stream>>>(hcur, gs, part);
  k_pool2<<<dim3(BB, TT), 128, 0, stream>>>(part, gs, pooled);
  gemm_part<<<dim3(512 / 32, 2), 256, 0, stream>>>(pooled, 256, n2t_w, 512, P, 512);
  k_n2t_reduce<<<(48 * 512 + 255) / 256, 256, 0, stream>>>(P, n2t_b, happ);
  k_mot<<<(BB * (TT - 1) * 256 + 255) / 256, 256, 0, stream>>>(happ, (float*)d_out + BB * TT * TOKF);

  // ---- transformer encoder ----
  float* hx = happ;
  for (int l = 0; l < 2; ++l) {
    gemm_part<<<dim3(1536 / 32, 4), 256, 0, stream>>>(hx, 512,
        tf_wqkv + (size_t)l * 512 * 1536, 1536, P, 1536);
    k_attn<<<dim3(NHH, BB), 64, 0, stream>>>(P, tf_bqkv + l * 1536, aoutb);
    gemm_part<<<dim3(512 / 32, 4), 256, 0, stream>>>(aoutb, 512,
        tf_wo + (size_t)l * 512 * 512, 512, P, 512);
    k_res_ln_p<<<BB * TT, 256, 0, stream>>>(P, 4, tf_bo + l * 512, hx,
        tf_ln1g + l * 512, tf_ln1b + l * 512, happ2);
    // FF: w1 partials -> P ; w2 reads relu(bias+P) directly, writes partials -> P2
    gemm_part<<<dim3(2048 / 32, 4), 256, 0, stream>>>(happ2, 512,
        tf_w1 + (size_t)l * 512 * 2048, 2048, P, 2048);
    gemm_part_pr<<<dim3(512 / 32, 16), 256, 0, stream>>>(P, 4, tf_b1 + l * 2048,
        tf_w2 + (size_t)l * 2048 * 512, 512, P2, 512);
    float* dst = (l == 1) ? (float*)d_out : happ;
    k_res_ln_p<<<BB * TT, 256, 0, stream>>>(P2, 16, tf_b2 + l * 512, happ2,
        tf_ln2g + l * 512, tf_ln2b + l * 512, dst);
    hx = happ;
  }
}